// Round 1
// baseline (464.296 us; speedup 1.0000x reference)
//
#include <hip/hip_runtime.h>

#define FEAT 256
#define HID 128
#define NKEYS 2

typedef __bf16 bf16x8 __attribute__((ext_vector_type(8)));
typedef float f32x16 __attribute__((ext_vector_type(16)));

union Frag {
    bf16x8 v;
    unsigned u[4];
    uint4 q;
};

// pack two f32 -> two bf16 (round-half-up) in one v_perm
__device__ __forceinline__ unsigned pack_bf16_2(float f0, float f1) {
    unsigned u0 = __float_as_uint(f0) + 0x8000u;
    unsigned u1 = __float_as_uint(f1) + 0x8000u;
    return __builtin_amdgcn_perm(u1, u0, 0x07060302u);
}

// shifted softplus: softplus(x) - ln2
__device__ __forceinline__ float ssp(float x) {
    float sp = __logf(1.0f + __expf(x));
    sp = (x > 15.0f) ? x : sp;
    return sp - 0.69314718056f;
}

// largest m with off[m] <= g  (off[0]=0, off sorted, n_mols+1 entries)
__device__ __forceinline__ int find_mol(const int* __restrict__ off, int n_mols, int g) {
    int lo = 0, hi = n_mols;
    while (hi - lo > 1) {
        int mid = (lo + hi) >> 1;
        if (off[mid] <= g) lo = mid; else hi = mid;
    }
    return lo;
}

// Block 0: prefix-scan num_atoms (int32, falling back to int64 if the int32
// interpretation doesn't sum to n_atoms). Blocks 1..256: pack W1 -> Bp bf16,
// layout Bp[c][k] (c = key*HID + j, k = feature), k contiguous.
__global__ void prep_kernel(const void* __restrict__ num_atoms_raw,
                            const float* __restrict__ W1,
                            int n_mols, int n_atoms,
                            int* __restrict__ off,
                            unsigned short* __restrict__ Bp) {
    if (blockIdx.x > 0) {
        int idx = (blockIdx.x - 1) * 256 + threadIdx.x;   // 0..65535
        int c = idx >> 8;
        int k = idx & 255;
        int key = c >> 7, j = c & 127;
        float f = W1[(size_t)key * FEAT * HID + (size_t)k * HID + j];
        unsigned u = __float_as_uint(f);
        unsigned r = (u + 0x7FFFu + ((u >> 16) & 1u)) >> 16;   // RNE to bf16
        Bp[(size_t)c * FEAT + k] = (unsigned short)r;
        return;
    }
    __shared__ long long tsum[256];
    __shared__ int csum[257];
    __shared__ int mode_sh;
    int tid = threadIdx.x;
    const int* a32 = (const int*)num_atoms_raw;
    const long long* a64 = (const long long*)num_atoms_raw;
    int chunk = (n_mols + 255) >> 8;
    int lo = tid * chunk;
    if (lo > n_mols) lo = n_mols;
    int hi = lo + chunk;
    if (hi > n_mols) hi = n_mols;
    long long s = 0;
    for (int i = lo; i < hi; ++i) s += (long long)a32[i];
    tsum[tid] = s;
    __syncthreads();
    if (tid == 0) {
        long long t = 0;
        for (int i = 0; i < 256; ++i) t += tsum[i];
        mode_sh = (t == (long long)n_atoms) ? 0 : 1;
    }
    __syncthreads();
    int mode = mode_sh;
    if (mode) {                      // only touch int64 view if int32 failed
        s = 0;
        for (int i = lo; i < hi; ++i) s += a64[i];
        tsum[tid] = s;
    }
    csum[tid] = (int)tsum[tid];
    __syncthreads();
    if (tid == 0) {
        int run = 0;
        for (int i = 0; i < 256; ++i) { int v = csum[i]; csum[i] = run; run += v; }
    }
    __syncthreads();
    int run = csum[tid];
    for (int i = lo; i < hi; ++i) {
        off[i] = run;
        run += mode ? (int)a64[i] : a32[i];
    }
    if (hi >= n_mols) off[n_mols] = run;
}

// Fused: C = s_i @ B (bf16 MFMA, fp32 acc), +b1, shifted-softplus, .W2, +b2,
// segment-sum into out[key][mol] via atomics.
// Block: 256 threads = 4 waves; tile 64 rows x 256 cols; wave = 64x64.
__global__ __launch_bounds__(256, 3)
void gemm_fused(const float* __restrict__ A,
                const unsigned short* __restrict__ Bp,
                const float* __restrict__ b1,
                const float* __restrict__ W2,
                const float* __restrict__ b2,
                const int* __restrict__ off,
                float* __restrict__ out,
                int n_atoms, int n_mols) {
    __shared__ float part[4][64];        // [wn][row]
    __shared__ float molacc[NKEYS][4];

    const int tid  = threadIdx.x;
    const int lane = tid & 63;
    const int wn   = tid >> 6;           // 0..3: 64-col group
    const int l31  = lane & 31;
    const int half = lane >> 5;          // 0/1
    const int m0   = blockIdx.x * 64;

    int row0 = m0 + l31;
    int row1 = row0 + 32;
    int r0 = min(row0, n_atoms - 1);
    int r1 = min(row1, n_atoms - 1);
    const float4* a0p = (const float4*)(A + (size_t)r0 * FEAT + half * 8);
    const float4* a1p = (const float4*)(A + (size_t)r1 * FEAT + half * 8);
    const int c0 = wn * 64 + l31;
    const Frag* b0p = (const Frag*)(Bp + (size_t)c0 * FEAT + half * 8);
    const Frag* b1p = (const Frag*)(Bp + (size_t)(c0 + 32) * FEAT + half * 8);

    f32x16 acc00 = 0.0f, acc01 = 0.0f, acc10 = 0.0f, acc11 = 0.0f;

    #pragma unroll
    for (int kk = 0; kk < FEAT / 16; ++kk) {
        float4 a0lo = a0p[4 * kk], a0hi = a0p[4 * kk + 1];
        float4 a1lo = a1p[4 * kk], a1hi = a1p[4 * kk + 1];
        Frag bf0 = b0p[2 * kk];
        Frag bf1 = b1p[2 * kk];
        Frag af0, af1;
        af0.u[0] = pack_bf16_2(a0lo.x, a0lo.y);
        af0.u[1] = pack_bf16_2(a0lo.z, a0lo.w);
        af0.u[2] = pack_bf16_2(a0hi.x, a0hi.y);
        af0.u[3] = pack_bf16_2(a0hi.z, a0hi.w);
        af1.u[0] = pack_bf16_2(a1lo.x, a1lo.y);
        af1.u[1] = pack_bf16_2(a1lo.z, a1lo.w);
        af1.u[2] = pack_bf16_2(a1hi.x, a1hi.y);
        af1.u[3] = pack_bf16_2(a1hi.z, a1hi.w);
        acc00 = __builtin_amdgcn_mfma_f32_32x32x16_bf16(af0.v, bf0.v, acc00, 0, 0, 0);
        acc01 = __builtin_amdgcn_mfma_f32_32x32x16_bf16(af0.v, bf1.v, acc01, 0, 0, 0);
        acc10 = __builtin_amdgcn_mfma_f32_32x32x16_bf16(af1.v, bf0.v, acc10, 0, 0, 0);
        acc11 = __builtin_amdgcn_mfma_f32_32x32x16_bf16(af1.v, bf1.v, acc11, 0, 0, 0);
    }

    if (tid < NKEYS * 4) molacc[tid >> 2][tid & 3] = 0.0f;

    float b1c0 = b1[c0], b1c1 = b1[c0 + 32];
    float w2c0 = W2[c0], w2c1 = W2[c0 + 32];

    // epilogue: act + .W2, column-reduce per row, stash in LDS
    #pragma unroll
    for (int rt = 0; rt < 2; ++rt) {
        const f32x16& Ac0 = rt ? acc10 : acc00;
        const f32x16& Ac1 = rt ? acc11 : acc01;
        #pragma unroll
        for (int r = 0; r < 16; ++r) {
            float t = ssp(Ac0[r] + b1c0) * w2c0 + ssp(Ac1[r] + b1c1) * w2c1;
            t += __shfl_xor(t, 1);
            t += __shfl_xor(t, 2);
            t += __shfl_xor(t, 4);
            t += __shfl_xor(t, 8);
            t += __shfl_xor(t, 16);
            if (l31 == r) {
                int row = rt * 32 + (r & 3) + 8 * (r >> 2) + 4 * half;
                part[wn][row] = t;
            }
        }
    }
    __syncthreads();

    if (tid < NKEYS * 64) {
        int key = tid >> 6, r = tid & 63;
        int gm = m0 + r;
        if (gm < n_atoms) {
            float val = part[2 * key][r] + part[2 * key + 1][r] + b2[key];
            int mol  = find_mol(off, n_mols, gm);
            int mol0 = find_mol(off, n_mols, m0);
            int ml = mol - mol0;
            if (ml < 4) atomicAdd(&molacc[key][ml], val);
            else        atomicAdd(&out[(size_t)key * n_mols + mol], val);
        }
    }
    __syncthreads();

    if (tid < NKEYS * 4) {
        int key = tid >> 2, ml = tid & 3;
        int mol0 = find_mol(off, n_mols, m0);
        int mol = mol0 + ml;
        if (mol < n_mols) {
            float v = molacc[key][ml];
            if (v != 0.0f) atomicAdd(&out[(size_t)key * n_mols + mol], v);
        }
    }
}

extern "C" void kernel_launch(void* const* d_in, const int* in_sizes, int n_in,
                              void* d_out, int out_size, void* d_ws, size_t ws_size,
                              hipStream_t stream) {
    const float* s_i      = (const float*)d_in[0];
    // d_in[1] = xyz: unused by the reference output
    const void*  num_atoms = d_in[2];
    const float* W1 = (const float*)d_in[3];
    const float* b1 = (const float*)d_in[4];
    const float* W2 = (const float*)d_in[5];
    const float* b2 = (const float*)d_in[6];
    int n_atoms = in_sizes[0] / FEAT;
    int n_mols  = in_sizes[2];
    float* out = (float*)d_out;

    int* off = (int*)d_ws;
    size_t off_bytes = (((size_t)(n_mols + 1) * 4) + 255) & ~(size_t)255;
    unsigned short* Bp = (unsigned short*)((char*)d_ws + off_bytes);

    hipMemsetAsync(d_out, 0, (size_t)out_size * sizeof(float), stream);

    int pack_blocks = (NKEYS * HID * FEAT) / 256;   // 256
    prep_kernel<<<1 + pack_blocks, 256, 0, stream>>>(num_atoms, W1, n_mols, n_atoms, off, Bp);

    int gblocks = (n_atoms + 63) / 64;
    gemm_fused<<<gblocks, 256, 0, stream>>>(s_i, Bp, b1, W2, b2, off, out, n_atoms, n_mols);
}

// Round 2
// 349.736 us; speedup vs baseline: 1.3276x; 1.3276x over previous
//
#include <hip/hip_runtime.h>

#define FEAT 256
#define HID 128
#define NKEYS 2

typedef __bf16 bf16x8 __attribute__((ext_vector_type(8)));
typedef float f32x16 __attribute__((ext_vector_type(16)));

union Frag {
    bf16x8 v;
    unsigned u[4];
    uint4 q;
};

// pack two f32 -> two bf16 (round-half-up) in one v_perm
__device__ __forceinline__ unsigned pack_bf16_2(float f0, float f1) {
    unsigned u0 = __float_as_uint(f0) + 0x8000u;
    unsigned u1 = __float_as_uint(f1) + 0x8000u;
    return __builtin_amdgcn_perm(u1, u0, 0x07060302u);
}

// shifted softplus: softplus(x) - ln2
__device__ __forceinline__ float ssp(float x) {
    float sp = __logf(1.0f + __expf(x));
    sp = (x > 15.0f) ? x : sp;
    return sp - 0.69314718056f;
}

// largest m with off[m] <= g  (off[0]=0, off sorted, n_mols+1 entries)
__device__ __forceinline__ int find_mol(const int* __restrict__ off, int n_mols, int g) {
    int lo = 0, hi = n_mols;
    while (hi - lo > 1) {
        int mid = (lo + hi) >> 1;
        if (off[mid] <= g) lo = mid; else hi = mid;
    }
    return lo;
}

// Block 0: prefix-scan num_atoms (int32, falling back to int64 if the int32
// interpretation doesn't sum to n_atoms) + zero d_out.
// Blocks 1..256: pack W1 -> Bp bf16, layout Bp[c][k] (c = key*HID + j).
__global__ void prep_kernel(const void* __restrict__ num_atoms_raw,
                            const float* __restrict__ W1,
                            int n_mols, int n_atoms,
                            int* __restrict__ off,
                            unsigned short* __restrict__ Bp,
                            float* __restrict__ out, int out_n) {
    if (blockIdx.x > 0) {
        int idx = (blockIdx.x - 1) * 256 + threadIdx.x;   // 0..65535
        int c = idx >> 8;
        int k = idx & 255;
        int key = c >> 7, j = c & 127;
        float f = W1[(size_t)key * FEAT * HID + (size_t)k * HID + j];
        unsigned u = __float_as_uint(f);
        unsigned r = (u + 0x7FFFu + ((u >> 16) & 1u)) >> 16;   // RNE to bf16
        Bp[(size_t)c * FEAT + k] = (unsigned short)r;
        return;
    }
    // zero the output (atomically accumulated by gemm_fused)
    for (int i = threadIdx.x; i < out_n; i += 256) out[i] = 0.0f;

    __shared__ long long tsum[256];
    __shared__ int csum[257];
    __shared__ int mode_sh;
    int tid = threadIdx.x;
    const int* a32 = (const int*)num_atoms_raw;
    const long long* a64 = (const long long*)num_atoms_raw;
    int chunk = (n_mols + 255) >> 8;
    int lo = tid * chunk;
    if (lo > n_mols) lo = n_mols;
    int hi = lo + chunk;
    if (hi > n_mols) hi = n_mols;
    long long s = 0;
    for (int i = lo; i < hi; ++i) s += (long long)a32[i];
    tsum[tid] = s;
    __syncthreads();
    if (tid == 0) {
        long long t = 0;
        for (int i = 0; i < 256; ++i) t += tsum[i];
        mode_sh = (t == (long long)n_atoms) ? 0 : 1;
    }
    __syncthreads();
    int mode = mode_sh;
    if (mode) {                      // only touch int64 view if int32 failed
        s = 0;
        for (int i = lo; i < hi; ++i) s += a64[i];
        tsum[tid] = s;
    }
    csum[tid] = (int)tsum[tid];
    __syncthreads();
    if (tid == 0) {
        int run = 0;
        for (int i = 0; i < 256; ++i) { int v = csum[i]; csum[i] = run; run += v; }
    }
    __syncthreads();
    int run = csum[tid];
    for (int i = lo; i < hi; ++i) {
        off[i] = run;
        run += mode ? (int)a64[i] : a32[i];
    }
    if (hi >= n_mols) off[n_mols] = run;
}

// Fused: C = s_i @ B (bf16 MFMA, fp32 acc), +b1, shifted-softplus, .W2, +b2,
// segment-sum into out[key][mol] via atomics.
// Block: 256 threads = 4 waves; tile 64 rows x 256 cols; wave = 64x64.
// A staged through an XOR-swizzled bf16 LDS tile (coalesced, convert-once).
__global__ __launch_bounds__(256, 2)
void gemm_fused(const float* __restrict__ A,
                const unsigned short* __restrict__ Bp,
                const float* __restrict__ b1,
                const float* __restrict__ W2,
                const float* __restrict__ b2,
                const int* __restrict__ off,
                float* __restrict__ out,
                int n_atoms, int n_mols) {
    // A chunk tile: 64 rows x 64 k (bf16) = 8 KB, as 16B units.
    // unit (row, u) stored at ldsA[row*8 + (u ^ (row&7))]  -> conflict-free
    __shared__ uint4 ldsA[64 * 8];
    __shared__ float part[4][64];        // [wn][row]
    __shared__ float molacc[NKEYS][4];

    const int tid  = threadIdx.x;
    const int lane = tid & 63;
    const int wn   = tid >> 6;           // 0..3: 64-col group
    const int l31  = lane & 31;
    const int half = lane >> 5;          // 0/1
    const int m0   = blockIdx.x * 64;

    // ---- staging role: thread t covers row t/4, 16 floats at seg (t&3)
    const int srow = tid >> 2;
    const int sseg = tid & 3;
    int grow = m0 + srow;
    if (grow > n_atoms - 1) grow = n_atoms - 1;
    const float4* gsrc = (const float4*)(A + (size_t)grow * FEAT + sseg * 16);
    const int wu0 = srow * 8 + (((sseg * 2)    ) ^ (srow & 7));
    const int wu1 = srow * 8 + (((sseg * 2) + 1) ^ (srow & 7));

    // ---- compute role
    const int c0 = wn * 64 + l31;
    const unsigned short* bb0 = Bp + (size_t)c0 * FEAT + half * 8;
    const unsigned short* bb1 = Bp + (size_t)(c0 + 32) * FEAT + half * 8;
    const int rbase0 = l31 * 8;            // row l31
    const int rbase1 = (l31 + 32) * 8;     // row l31+32 (same &7 swizzle)
    const int rxor = l31 & 7;

    f32x16 acc00 = 0.0f, acc01 = 0.0f, acc10 = 0.0f, acc11 = 0.0f;

    #pragma unroll
    for (int c = 0; c < FEAT / 64; ++c) {
        const int kb = c * 64;
        // B fragments for this chunk (global, L2-resident)
        Frag bf0[4], bf1[4];
        #pragma unroll
        for (int j = 0; j < 4; ++j) {
            bf0[j].q = *(const uint4*)(bb0 + kb + j * 16);
            bf1[j].q = *(const uint4*)(bb1 + kb + j * 16);
        }
        // A stage: global loads issued before the barrier (overlap prev MFMA)
        float4 f0 = gsrc[c * 16 + 0];
        float4 f1 = gsrc[c * 16 + 1];
        float4 f2 = gsrc[c * 16 + 2];
        float4 f3 = gsrc[c * 16 + 3];
        if (c > 0) __syncthreads();        // prev chunk fully consumed
        uint4 p0, p1;
        p0.x = pack_bf16_2(f0.x, f0.y);
        p0.y = pack_bf16_2(f0.z, f0.w);
        p0.z = pack_bf16_2(f1.x, f1.y);
        p0.w = pack_bf16_2(f1.z, f1.w);
        p1.x = pack_bf16_2(f2.x, f2.y);
        p1.y = pack_bf16_2(f2.z, f2.w);
        p1.z = pack_bf16_2(f3.x, f3.y);
        p1.w = pack_bf16_2(f3.z, f3.w);
        ldsA[wu0] = p0;
        ldsA[wu1] = p1;
        __syncthreads();

        #pragma unroll
        for (int j = 0; j < 4; ++j) {
            const int u = j * 2 + half;
            const int sw = u ^ rxor;
            Frag a0, a1;
            a0.q = ldsA[rbase0 + sw];
            a1.q = ldsA[rbase1 + sw];
            acc00 = __builtin_amdgcn_mfma_f32_32x32x16_bf16(a0.v, bf0[j].v, acc00, 0, 0, 0);
            acc01 = __builtin_amdgcn_mfma_f32_32x32x16_bf16(a0.v, bf1[j].v, acc01, 0, 0, 0);
            acc10 = __builtin_amdgcn_mfma_f32_32x32x16_bf16(a1.v, bf0[j].v, acc10, 0, 0, 0);
            acc11 = __builtin_amdgcn_mfma_f32_32x32x16_bf16(a1.v, bf1[j].v, acc11, 0, 0, 0);
        }
    }

    if (tid < NKEYS * 4) molacc[tid >> 2][tid & 3] = 0.0f;

    float b1c0 = b1[c0], b1c1 = b1[c0 + 32];
    float w2c0 = W2[c0], w2c1 = W2[c0 + 32];

    // epilogue: act + .W2, column-reduce per row, stash in LDS
    #pragma unroll
    for (int rt = 0; rt < 2; ++rt) {
        const f32x16& Ac0 = rt ? acc10 : acc00;
        const f32x16& Ac1 = rt ? acc11 : acc01;
        #pragma unroll
        for (int r = 0; r < 16; ++r) {
            float t = ssp(Ac0[r] + b1c0) * w2c0 + ssp(Ac1[r] + b1c1) * w2c1;
            t += __shfl_xor(t, 1);
            t += __shfl_xor(t, 2);
            t += __shfl_xor(t, 4);
            t += __shfl_xor(t, 8);
            t += __shfl_xor(t, 16);
            if (l31 == r) {
                int row = rt * 32 + (r & 3) + 8 * (r >> 2) + 4 * half;
                part[wn][row] = t;
            }
        }
    }
    __syncthreads();

    if (tid < NKEYS * 64) {
        int key = tid >> 6, r = tid & 63;
        int gm = m0 + r;
        if (gm < n_atoms) {
            float val = part[2 * key][r] + part[2 * key + 1][r] + b2[key];
            int mol  = find_mol(off, n_mols, gm);
            int mol0 = find_mol(off, n_mols, m0);
            int ml = mol - mol0;
            if (ml < 4) atomicAdd(&molacc[key][ml], val);
            else        atomicAdd(&out[(size_t)key * n_mols + mol], val);
        }
    }
    __syncthreads();

    if (tid < NKEYS * 4) {
        int key = tid >> 2, ml = tid & 3;
        int mol0 = find_mol(off, n_mols, m0);
        int mol = mol0 + ml;
        if (mol < n_mols) {
            float v = molacc[key][ml];
            if (v != 0.0f) atomicAdd(&out[(size_t)key * n_mols + mol], v);
        }
    }
}

extern "C" void kernel_launch(void* const* d_in, const int* in_sizes, int n_in,
                              void* d_out, int out_size, void* d_ws, size_t ws_size,
                              hipStream_t stream) {
    const float* s_i      = (const float*)d_in[0];
    // d_in[1] = xyz: unused by the reference output
    const void*  num_atoms = d_in[2];
    const float* W1 = (const float*)d_in[3];
    const float* b1 = (const float*)d_in[4];
    const float* W2 = (const float*)d_in[5];
    const float* b2 = (const float*)d_in[6];
    int n_atoms = in_sizes[0] / FEAT;
    int n_mols  = in_sizes[2];
    float* out = (float*)d_out;

    int* off = (int*)d_ws;
    size_t off_bytes = (((size_t)(n_mols + 1) * 4) + 255) & ~(size_t)255;
    unsigned short* Bp = (unsigned short*)((char*)d_ws + off_bytes);

    int pack_blocks = (NKEYS * HID * FEAT) / 256;   // 256
    prep_kernel<<<1 + pack_blocks, 256, 0, stream>>>(num_atoms, W1, n_mols, n_atoms,
                                                     off, Bp, out, out_size);

    int gblocks = (n_atoms + 63) / 64;
    gemm_fused<<<gblocks, 256, 0, stream>>>(s_i, Bp, b1, W2, b2, off, out, n_atoms, n_mols);
}